// Round 10
// baseline (129.310 us; speedup 1.0000x reference)
//
#include <hip/hip_runtime.h>

// Problem constants
#define T_LEN 4096
#define N_WIN 3969          // T - L + 1
#define K_SH  128
#define L_SH  128
#define B_SZ  256

#define SSTR  136           // S row stride (bf16 elems), 272 B
// x copy stride (bf16): 8720 B; stride/4 ≡ 4 (mod 32) -> 8 copy bases on distinct
// banks. Padded so the last tile's reads stay in range.
#define XSTR  4360

typedef __attribute__((ext_vector_type(8))) __bf16 bf16x8;
typedef __attribute__((ext_vector_type(4))) float f32x4;
typedef _Float16 h2 __attribute__((ext_vector_type(2)));   // packed half pair

__device__ __forceinline__ unsigned short f2bf(float f) {
    union { float f; unsigned int u; } c; c.f = f;
    unsigned int u = c.u + 0x7fff + ((c.u >> 16) & 1u);
    return (unsigned short)(u >> 16);
}
__device__ __forceinline__ unsigned int pack2(unsigned short lo, unsigned short hi) {
    return (unsigned int)lo | ((unsigned int)hi << 16);
}

// ---- packed-f16 selection primitives (each op handles BOTH lists) ----
__device__ __forceinline__ h2 max2(h2 a, h2 b) { return __builtin_elementwise_max(a, b); }
__device__ __forceinline__ h2 min2(h2 a, h2 b) { return __builtin_elementwise_min(a, b); }
__device__ __forceinline__ h2 cvt2(float lo, float hi) {   // lo -> elem0, hi -> elem1
    return __builtin_bit_cast(h2, __builtin_amdgcn_cvt_pkrtz(lo, hi));
}
__device__ __forceinline__ void ce2(h2& hi, h2& lo) {
    const h2 m = max2(hi, lo);
    lo = min2(hi, lo);
    hi = m;
}
__device__ __forceinline__ void sort4_2(h2& a, h2& b, h2& c, h2& d) {
    ce2(a, b); ce2(c, d); ce2(a, c); ce2(b, d); ce2(b, c);
}
// top-5 of two descending sorted 4-lists (odd-even merge, 8 comparators)
__device__ __forceinline__ void merge44_top5_2(h2 a0, h2 a1, h2 a2, h2 a3,
                                               h2 b0, h2 b1, h2 b2, h2 b3,
                                               h2& r0, h2& r1, h2& r2, h2& r3, h2& r4) {
    ce2(a0, b0); ce2(a2, b2); ce2(b0, a2);
    ce2(a1, b1); ce2(a3, b3); ce2(b1, a3);
    r0 = a0;
    r1 = a1; r2 = b0; ce2(r1, r2);
    r3 = b1; r4 = a2; ce2(r3, r4);
}
// r = top-5 of union of two descending sorted 5-lists (c_k = max_{i+j=k} min(a_i,b_j))
__device__ __forceinline__ void merge55_2(h2& r0, h2& r1, h2& r2, h2& r3, h2& r4,
                                          h2 s0, h2 s1, h2 s2, h2 s3, h2 s4) {
    const h2 m00 = min2(r0, s0);
    const h2 m10 = min2(r1, s0), m01 = min2(r0, s1);
    const h2 m20 = min2(r2, s0), m11 = min2(r1, s1), m02 = min2(r0, s2);
    const h2 m30 = min2(r3, s0), m21 = min2(r2, s1), m12 = min2(r1, s2), m03 = min2(r0, s3);
    const h2 n0 = max2(r0, s0);
    const h2 n1 = max2(max2(r1, s1), m00);
    const h2 n2 = max2(max2(r2, s2), max2(m10, m01));
    const h2 n3 = max2(max2(max2(r3, s3), m20), max2(m11, m02));
    const h2 n4 = max2(max2(max2(r4, s4), max2(m30, m03)), max2(m21, m12));
    r0 = n0; r1 = n1; r2 = n2; r3 = n3; r4 = n4;
}
// packed single-value insert (epilogue only)
__device__ __forceinline__ void insert1_2(h2 v, h2* rt) {
    h2 b = max2(rt[4], v); h2 m;
    m = max2(rt[3], b);     b     = min2(rt[3], b);     rt[3] = m;
    m = max2(rt[2], rt[3]); rt[3] = min2(rt[2], rt[3]); rt[2] = m;
    m = max2(rt[1], rt[2]); rt[2] = min2(rt[1], rt[2]); rt[1] = m;
    m = max2(rt[0], rt[1]); rt[1] = min2(rt[0], rt[1]); rt[0] = m;
    rt[4] = b;
}
// per-tile: fold 32 acc values (16 per list) into packed running top-5
__device__ __forceinline__ void select32(const f32x4* acc0, const f32x4* acc1, h2* rt) {
    h2 p[16];
    #pragma unroll
    for (int m = 0; m < 4; ++m)
        #pragma unroll
        for (int i = 0; i < 4; ++i)
            p[4 * m + i] = cvt2(acc0[m][i], acc1[m][i]);
    sort4_2(p[0], p[1], p[2],  p[3]);
    sort4_2(p[4], p[5], p[6],  p[7]);
    sort4_2(p[8], p[9], p[10], p[11]);
    sort4_2(p[12], p[13], p[14], p[15]);
    h2 u0, u1, u2, u3, u4, v0, v1, v2, v3, v4;
    merge44_top5_2(p[0], p[1], p[2],  p[3],  p[4],  p[5],  p[6],  p[7],  u0, u1, u2, u3, u4);
    merge44_top5_2(p[8], p[9], p[10], p[11], p[12], p[13], p[14], p[15], v0, v1, v2, v3, v4);
    merge55_2(u0, u1, u2, u3, u4, v0, v1, v2, v3, v4);
    merge55_2(rt[0], rt[1], rt[2], rt[3], rt[4], u0, u1, u2, u3, u4);
}

// Round-10 kernel: identical structure to round 9 (16 waves x 64 shapelets/wave,
// halved LDS A-traffic + 4 waves/SIMD), with ONE change: __launch_bounds__(1024)
// with NO second argument.
//
// WHY: reconciling rounds 2/4/7/8/9, the toolchain treats the 2nd arg like
// CUDA's min-BLOCKS-per-CU: (1024,4) -> 64 waves/CU demanded -> clamped to
// 8 waves/EU -> VGPR cap 64. R9's natural live set is ~88 (measured in R8
// under its true cap of 128), so R9 spilled 67 MB and reported VGPR=64=cap.
// A 1024-thread block already structurally requires 4 waves/SIMD (cap 128),
// which fits 88 with headroom — no second arg needed, no spill possible.
//
// Wave w (0..15): wp = w&1 shapelet half [64wp, 64wp+64); G = w>>1 (0..7)
// window group. Step s: windows 512s + 64G + [0,64). G<6: 8 steps, G>=6: 7.
// Boundary window 3968 handled by G==6 waves (both wp).
__global__ __launch_bounds__(1024)
void shapelet_fused16_kernel(const float* __restrict__ x,
                             const float* __restrict__ s,
                             float* __restrict__ out) {
    __shared__ __align__(16) unsigned short ldsS[K_SH * SSTR];   // 34816 B
    __shared__ __align__(16) unsigned short ldsX[8 * XSTR];      // 69760 B

    const int t    = threadIdx.x;
    const int lane = t & 63;
    const int w    = t >> 6;          // 0..15
    const int r    = lane & 15;
    const int q    = lane >> 4;
    const int c7   = lane & 7;
    const int ub   = (lane >> 3) & 1;
    const int wp   = w & 1;           // shapelet half (64 each)
    const int G    = w >> 1;          // window group 0..7 (64 windows/step)
    const int b    = blockIdx.x;

    // ---- stage centered S as bf16: 8 threads per row k, 16 elems each ----
    {
        const int k = t >> 3, e8 = t & 7;
        const float4* srow = (const float4*)(s + k * L_SH + e8 * 16);
        float4 v[4];
        float sum = 0.0f;
        #pragma unroll
        for (int j = 0; j < 4; ++j) {
            v[j] = srow[j];
            sum += (v[j].x + v[j].y) + (v[j].z + v[j].w);
        }
        sum += __shfl_xor(sum, 1);
        sum += __shfl_xor(sum, 2);
        sum += __shfl_xor(sum, 4);
        const float mean = sum * (1.0f / 128.0f);
        uint4* dst = (uint4*)((char*)ldsS + k * (SSTR * 2) + e8 * 32);
        #pragma unroll
        for (int j = 0; j < 2; ++j) {
            uint4 o;
            o.x = pack2(f2bf(v[2*j].x - mean),   f2bf(v[2*j].y - mean));
            o.y = pack2(f2bf(v[2*j].z - mean),   f2bf(v[2*j].w - mean));
            o.z = pack2(f2bf(v[2*j+1].x - mean), f2bf(v[2*j+1].y - mean));
            o.w = pack2(f2bf(v[2*j+1].z - mean), f2bf(v[2*j+1].w - mean));
            dst[j] = o;
        }
        if (e8 == 7) *(uint4*)((char*)ldsS + k * (SSTR * 2) + 256) = make_uint4(0,0,0,0);
    }

    // ---- stage x row as 8 shifted bf16 copies (conflict-free write map) ----
    {
        const float* __restrict__ xb = x + (size_t)b * T_LEN;
        const int a = (t ^ (t >> 3)) & 7;
        for (int i = (t >> 3); i < XSTR / 8; i += 128) {
            const int p0 = 8 * i;
            float xv[16];
            if (p0 + 16 <= T_LEN) {
                const float4* sp = (const float4*)(xb + p0);
                #pragma unroll
                for (int j = 0; j < 4; ++j) *(float4*)(xv + 4 * j) = sp[j];
            } else {
                #pragma unroll
                for (int j = 0; j < 16; ++j) {
                    const int gi = p0 + j;
                    xv[j] = (gi < T_LEN) ? xb[gi] : 0.0f;
                }
            }
            unsigned short bv[16];
            #pragma unroll
            for (int j = 0; j < 16; ++j) bv[j] = f2bf(xv[j]);
            uint4 o;
            o.x = pack2(bv[a],     bv[a + 1]);
            o.y = pack2(bv[a + 2], bv[a + 3]);
            o.z = pack2(bv[a + 4], bv[a + 5]);
            o.w = pack2(bv[a + 6], bv[a + 7]);
            *(uint4*)((char*)ldsX + a * (XSTR * 2) + 2 * p0) = o;
        }
    }
    __syncthreads();

    // ---- hoist B fragments: 4 kt16 tiles (64 shapelets) x 4 K-chunks ----
    bf16x8 bfr[4][4];
    #pragma unroll
    for (int kt = 0; kt < 4; ++kt)
        #pragma unroll
        for (int c = 0; c < 4; ++c)
            bfr[kt][c] = __builtin_bit_cast(bf16x8, *(const uint4*)(
                (const char*)ldsS + ((64 * wp + 16 * kt + r)) * (SSTR * 2) + 64 * c + 16 * q));

    // two packed running top-5 sets:
    // rtP: elem0 -> ks = 64wp +      r, elem1 -> ks = 64wp + 16 + r  (kt 0,1)
    // rtQ: elem0 -> ks = 64wp + 32 + r, elem1 -> ks = 64wp + 48 + r  (kt 2,3)
    h2 rtP[5], rtQ[5];
    #pragma unroll
    for (int i = 0; i < 5; ++i) {
        rtP[i] = __builtin_bit_cast(h2, 0xFC00FC00u);
        rtQ[i] = __builtin_bit_cast(h2, 0xFC00FC00u);
    }

    // group G starts at byte 128*G (window 64*G); advances 1024 B (512 windows)
    const char* xp = (const char*)ldsX + c7 * (XSTR * 2) + 16 * q + 16 * ub
                   + G * 128;

    const f32x4 ZCC = (f32x4){0.f, 0.f, 0.f, 0.f};

    // Per step: ONE afr load set feeds TWO kt-pair MFMA passes (R8's LDS win).
#define TILE_STEP                                                               \
    {                                                                           \
        bf16x8 afr[10];                                                         \
        _Pragma("unroll")                                                       \
        for (int j = 0; j < 10; ++j)                                            \
            afr[j] = __builtin_bit_cast(bf16x8, *(const uint4*)(xp + 32 * j));  \
        xp += 1024;                                                             \
        f32x4 acc0[4], acc1[4];                                                 \
        _Pragma("unroll")                                                       \
        for (int m = 0; m < 4; ++m) {                                           \
            acc0[m] = __builtin_amdgcn_mfma_f32_16x16x32_bf16(afr[m], bfr[0][0], ZCC, 0, 0, 0); \
            acc1[m] = __builtin_amdgcn_mfma_f32_16x16x32_bf16(afr[m], bfr[1][0], ZCC, 0, 0, 0); \
        }                                                                       \
        _Pragma("unroll")                                                       \
        for (int c = 1; c < 4; ++c) {                                           \
            _Pragma("unroll")                                                   \
            for (int m = 0; m < 4; ++m) {                                       \
                acc0[m] = __builtin_amdgcn_mfma_f32_16x16x32_bf16(afr[m + 2*c], bfr[0][c], acc0[m], 0, 0, 0); \
                acc1[m] = __builtin_amdgcn_mfma_f32_16x16x32_bf16(afr[m + 2*c], bfr[1][c], acc1[m], 0, 0, 0); \
            }                                                                   \
        }                                                                       \
        select32(acc0, acc1, rtP);                                              \
        _Pragma("unroll")                                                       \
        for (int m = 0; m < 4; ++m) {                                           \
            acc0[m] = __builtin_amdgcn_mfma_f32_16x16x32_bf16(afr[m], bfr[2][0], ZCC, 0, 0, 0); \
            acc1[m] = __builtin_amdgcn_mfma_f32_16x16x32_bf16(afr[m], bfr[3][0], ZCC, 0, 0, 0); \
        }                                                                       \
        _Pragma("unroll")                                                       \
        for (int c = 1; c < 4; ++c) {                                           \
            _Pragma("unroll")                                                   \
            for (int m = 0; m < 4; ++m) {                                       \
                acc0[m] = __builtin_amdgcn_mfma_f32_16x16x32_bf16(afr[m + 2*c], bfr[2][c], acc0[m], 0, 0, 0); \
                acc1[m] = __builtin_amdgcn_mfma_f32_16x16x32_bf16(afr[m + 2*c], bfr[3][c], acc1[m], 0, 0, 0); \
            }                                                                   \
        }                                                                       \
        select32(acc0, acc1, rtQ);                                              \
    }

    // windows 512s + 64G + [0,64): G<6 -> s=0..7, G>=6 -> s=0..6
    const int nst = (G < 6) ? 8 : 7;
    for (int st = 0; st < nst; ++st) { TILE_STEP }
#undef TILE_STEP

    // ---- boundary window n = 3968 (byte 7936) -> G==6 waves (both wp) ----
    if (G == 6) {
        f32x4 e[4];
        #pragma unroll
        for (int kt = 0; kt < 4; ++kt) e[kt] = (f32x4){0.f, 0.f, 0.f, 0.f};
        const char* eb = (const char*)ldsX + c7 * (XSTR * 2) + 7936 + 16 * q + 16 * ub;
        #pragma unroll
        for (int c = 0; c < 4; ++c) {
            const bf16x8 af = __builtin_bit_cast(bf16x8, *(const uint4*)(eb + 64 * c));
            #pragma unroll
            for (int kt = 0; kt < 4; ++kt)
                e[kt] = __builtin_amdgcn_mfma_f32_16x16x32_bf16(af, bfr[kt][c], e[kt], 0, 0, 0);
        }
        if (q == 0) {
            insert1_2(cvt2(e[0][0], e[1][0]), rtP);
            insert1_2(cvt2(e[2][0], e[3][0]), rtQ);
        }
    }

    // ---- butterfly merge across quads for both sets ----
    #pragma unroll
    for (int mask = 16; mask <= 32; mask <<= 1) {
        h2 sv[5], sw[5];
        #pragma unroll
        for (int i = 0; i < 5; ++i) {
            sv[i] = __builtin_bit_cast(h2, __shfl_xor(__builtin_bit_cast(int, rtP[i]), mask));
            sw[i] = __builtin_bit_cast(h2, __shfl_xor(__builtin_bit_cast(int, rtQ[i]), mask));
        }
        merge55_2(rtP[0], rtP[1], rtP[2], rtP[3], rtP[4], sv[0], sv[1], sv[2], sv[3], sv[4]);
        merge55_2(rtQ[0], rtQ[1], rtQ[2], rtQ[3], rtQ[4], sw[0], sw[1], sw[2], sw[3], sw[4]);
    }

    // ---- cross-G merge via LDS; per wp: 7 writers (G!=0), reader G==0 ----
    __syncthreads();   // ldsS reads (bfr hoist) long done; reuse as scratch
    unsigned int* pbuf = (unsigned int*)ldsS;   // [(wp*7 + G-1)*16 + r][10]
    if (G != 0 && q == 0) {
        unsigned int* p = pbuf + ((wp * 7 + (G - 1)) * 16 + r) * 10;
        #pragma unroll
        for (int i = 0; i < 5; ++i) {
            p[i]     = __builtin_bit_cast(unsigned int, rtP[i]);
            p[5 + i] = __builtin_bit_cast(unsigned int, rtQ[i]);
        }
    }
    __syncthreads();
    if (G == 0 && q == 0) {
        #pragma unroll
        for (int reg = 0; reg < 7; ++reg) {
            const unsigned int* p = pbuf + ((wp * 7 + reg) * 16 + r) * 10;
            h2 sv[5], sw[5];
            #pragma unroll
            for (int i = 0; i < 5; ++i) {
                sv[i] = __builtin_bit_cast(h2, p[i]);
                sw[i] = __builtin_bit_cast(h2, p[5 + i]);
            }
            merge55_2(rtP[0], rtP[1], rtP[2], rtP[3], rtP[4], sv[0], sv[1], sv[2], sv[3], sv[4]);
            merge55_2(rtQ[0], rtQ[1], rtQ[2], rtQ[3], rtQ[4], sw[0], sw[1], sw[2], sw[3], sw[4]);
        }

        // emit features for 4 lists: ks = 64wp + {0,16,32,48} + r
        float* ob = out + (size_t)b * (4 * K_SH);
        const h2* rts[2] = { rtP, rtQ };
        #pragma unroll
        for (int setI = 0; setI < 2; ++setI) {
            const h2* rt = rts[setI];
            const float A0 = (float)rt[0][0], A1 = (float)rt[1][0], A2 = (float)rt[2][0],
                        A3 = (float)rt[3][0], A4 = (float)rt[4][0];
            const float B0 = (float)rt[0][1], B1 = (float)rt[1][1], B2 = (float)rt[2][1],
                        B3 = (float)rt[3][1], B4 = (float)rt[4][1];
            const int ksA = 64 * wp + 32 * setI + r, ksB = ksA + 16;
            const float mA = (((A0 + A1) + (A2 + A3)) + A4) * 0.2f;
            const float mB = (((B0 + B1) + (B2 + B3)) + B4) * 0.2f;
            ob[ksA]           = A0;
            ob[K_SH + ksA]    = mA;
            ob[2*K_SH + ksA]  = A1;
            ob[3*K_SH + ksA]  = fmaxf(A0 - A1, 0.0f);
            ob[ksB]           = B0;
            ob[K_SH + ksB]    = mB;
            ob[2*K_SH + ksB]  = B1;
            ob[3*K_SH + ksB]  = fmaxf(B0 - B1, 0.0f);
        }
    }
}

extern "C" void kernel_launch(void* const* d_in, const int* in_sizes, int n_in,
                              void* d_out, int out_size, void* d_ws, size_t ws_size,
                              hipStream_t stream) {
    const float* x = (const float*)d_in[0];        // (256, 4096) fp32
    const float* s = (const float*)d_in[1];        // (128, 128)  fp32
    float* out = (float*)d_out;                    // (256, 512)  fp32
    shapelet_fused16_kernel<<<B_SZ, 1024, 0, stream>>>(x, s, out);
}

// Round 11
// 127.510 us; speedup vs baseline: 1.0141x; 1.0141x over previous
//
#include <hip/hip_runtime.h>

// Problem constants
#define T_LEN 4096
#define N_WIN 3969          // T - L + 1
#define K_SH  128
#define L_SH  128
#define B_SZ  256

#define SSTR  136           // S row stride (bf16 elems), 272 B
// x copy stride (bf16): 8720 B; stride/4 ≡ 4 (mod 32) -> 8 copy bases on distinct
// banks. Padded so the last tile's reads stay in range.
#define XSTR  4360

typedef __attribute__((ext_vector_type(8))) __bf16 bf16x8;
typedef __attribute__((ext_vector_type(4))) float f32x4;
typedef _Float16 h2 __attribute__((ext_vector_type(2)));   // packed half pair

__device__ __forceinline__ unsigned short f2bf(float f) {
    union { float f; unsigned int u; } c; c.f = f;
    unsigned int u = c.u + 0x7fff + ((c.u >> 16) & 1u);
    return (unsigned short)(u >> 16);
}
__device__ __forceinline__ unsigned int pack2(unsigned short lo, unsigned short hi) {
    return (unsigned int)lo | ((unsigned int)hi << 16);
}

// ---- packed-f16 selection primitives (each op handles BOTH lists) ----
__device__ __forceinline__ h2 max2(h2 a, h2 b) { return __builtin_elementwise_max(a, b); }
__device__ __forceinline__ h2 min2(h2 a, h2 b) { return __builtin_elementwise_min(a, b); }
__device__ __forceinline__ h2 cvt2(float lo, float hi) {   // lo -> elem0, hi -> elem1
    return __builtin_bit_cast(h2, __builtin_amdgcn_cvt_pkrtz(lo, hi));
}
__device__ __forceinline__ void ce2(h2& hi, h2& lo) {
    const h2 m = max2(hi, lo);
    lo = min2(hi, lo);
    hi = m;
}
__device__ __forceinline__ void sort4_2(h2& a, h2& b, h2& c, h2& d) {
    ce2(a, b); ce2(c, d); ce2(a, c); ce2(b, d); ce2(b, c);
}
// top-5 of two descending sorted 4-lists (odd-even merge, 8 comparators)
__device__ __forceinline__ void merge44_top5_2(h2 a0, h2 a1, h2 a2, h2 a3,
                                               h2 b0, h2 b1, h2 b2, h2 b3,
                                               h2& r0, h2& r1, h2& r2, h2& r3, h2& r4) {
    ce2(a0, b0); ce2(a2, b2); ce2(b0, a2);
    ce2(a1, b1); ce2(a3, b3); ce2(b1, a3);
    r0 = a0;
    r1 = a1; r2 = b0; ce2(r1, r2);
    r3 = b1; r4 = a2; ce2(r3, r4);
}
// r = top-5 of union of two descending sorted 5-lists (c_k = max_{i+j=k} min(a_i,b_j))
__device__ __forceinline__ void merge55_2(h2& r0, h2& r1, h2& r2, h2& r3, h2& r4,
                                          h2 s0, h2 s1, h2 s2, h2 s3, h2 s4) {
    const h2 m00 = min2(r0, s0);
    const h2 m10 = min2(r1, s0), m01 = min2(r0, s1);
    const h2 m20 = min2(r2, s0), m11 = min2(r1, s1), m02 = min2(r0, s2);
    const h2 m30 = min2(r3, s0), m21 = min2(r2, s1), m12 = min2(r1, s2), m03 = min2(r0, s3);
    const h2 n0 = max2(r0, s0);
    const h2 n1 = max2(max2(r1, s1), m00);
    const h2 n2 = max2(max2(r2, s2), max2(m10, m01));
    const h2 n3 = max2(max2(max2(r3, s3), m20), max2(m11, m02));
    const h2 n4 = max2(max2(max2(r4, s4), max2(m30, m03)), max2(m21, m12));
    r0 = n0; r1 = n1; r2 = n2; r3 = n3; r4 = n4;
}
// packed single-value insert (epilogue only)
__device__ __forceinline__ void insert1_2(h2 v, h2* rt) {
    h2 b = max2(rt[4], v); h2 m;
    m = max2(rt[3], b);     b     = min2(rt[3], b);     rt[3] = m;
    m = max2(rt[2], rt[3]); rt[3] = min2(rt[2], rt[3]); rt[2] = m;
    m = max2(rt[1], rt[2]); rt[2] = min2(rt[1], rt[2]); rt[1] = m;
    m = max2(rt[0], rt[1]); rt[1] = min2(rt[0], rt[1]); rt[0] = m;
    rt[4] = b;
}
// per-tile: fold 32 acc values (16 per list) into packed running top-5
__device__ __forceinline__ void select32(const f32x4* acc0, const f32x4* acc1, h2* rt) {
    h2 p[16];
    #pragma unroll
    for (int m = 0; m < 4; ++m)
        #pragma unroll
        for (int i = 0; i < 4; ++i)
            p[4 * m + i] = cvt2(acc0[m][i], acc1[m][i]);
    sort4_2(p[0], p[1], p[2],  p[3]);
    sort4_2(p[4], p[5], p[6],  p[7]);
    sort4_2(p[8], p[9], p[10], p[11]);
    sort4_2(p[12], p[13], p[14], p[15]);
    h2 u0, u1, u2, u3, u4, v0, v1, v2, v3, v4;
    merge44_top5_2(p[0], p[1], p[2],  p[3],  p[4],  p[5],  p[6],  p[7],  u0, u1, u2, u3, u4);
    merge44_top5_2(p[8], p[9], p[10], p[11], p[12], p[13], p[14], p[15], v0, v1, v2, v3, v4);
    merge55_2(u0, u1, u2, u3, u4, v0, v1, v2, v3, v4);
    merge55_2(rt[0], rt[1], rt[2], rt[3], rt[4], u0, u1, u2, u3, u4);
}

// Round-11 kernel: byte-identical to round 10 EXCEPT __launch_bounds__(1024, 1).
//
// Launch-bounds model (fitted to R2/R4/R5/R8/R9/R10 measurements): the 2nd arg
// acts like CUDA min-BLOCKS-per-CU; absent -> the backend targets max occupancy
// (8 waves/EU, VGPR cap 64) even at the cost of massive spill (R10: cap 64,
// 67 MB scratch). (1024,4): 4x16=64 waves/CU -> clamp 8/EU -> cap 64 (R9 spill,
// R4/R5 fit under 64). (512,2): 16 waves/CU = 4/EU -> cap 128 (R8: 88 regs, no
// spill). (1024,1): 16 waves/CU = 4 waves/EU -> cap 128 under EITHER semantics
// -> the ~88-reg live set of this structure (measured in R8) fits spill-free.
//
// Structure (validated piecewise): 16 waves x 64 shapelets/wave -> LDS A-frag
// traffic halved (R8: bank conflicts 2.75M->1.47M) + 4 waves/SIMD latency
// hiding (R4). Wave w: wp = w&1 shapelet half; G = w>>1 window group (0..7),
// step s: windows 512s + 64G + [0,64); G<6: 8 steps, G>=6: 7 steps; boundary
// window 3968 handled by G==6.
__global__ __launch_bounds__(1024, 1)
void shapelet_fused16_kernel(const float* __restrict__ x,
                             const float* __restrict__ s,
                             float* __restrict__ out) {
    __shared__ __align__(16) unsigned short ldsS[K_SH * SSTR];   // 34816 B
    __shared__ __align__(16) unsigned short ldsX[8 * XSTR];      // 69760 B

    const int t    = threadIdx.x;
    const int lane = t & 63;
    const int w    = t >> 6;          // 0..15
    const int r    = lane & 15;
    const int q    = lane >> 4;
    const int c7   = lane & 7;
    const int ub   = (lane >> 3) & 1;
    const int wp   = w & 1;           // shapelet half (64 each)
    const int G    = w >> 1;          // window group 0..7 (64 windows/step)
    const int b    = blockIdx.x;

    // ---- stage centered S as bf16: 8 threads per row k, 16 elems each ----
    {
        const int k = t >> 3, e8 = t & 7;
        const float4* srow = (const float4*)(s + k * L_SH + e8 * 16);
        float4 v[4];
        float sum = 0.0f;
        #pragma unroll
        for (int j = 0; j < 4; ++j) {
            v[j] = srow[j];
            sum += (v[j].x + v[j].y) + (v[j].z + v[j].w);
        }
        sum += __shfl_xor(sum, 1);
        sum += __shfl_xor(sum, 2);
        sum += __shfl_xor(sum, 4);
        const float mean = sum * (1.0f / 128.0f);
        uint4* dst = (uint4*)((char*)ldsS + k * (SSTR * 2) + e8 * 32);
        #pragma unroll
        for (int j = 0; j < 2; ++j) {
            uint4 o;
            o.x = pack2(f2bf(v[2*j].x - mean),   f2bf(v[2*j].y - mean));
            o.y = pack2(f2bf(v[2*j].z - mean),   f2bf(v[2*j].w - mean));
            o.z = pack2(f2bf(v[2*j+1].x - mean), f2bf(v[2*j+1].y - mean));
            o.w = pack2(f2bf(v[2*j+1].z - mean), f2bf(v[2*j+1].w - mean));
            dst[j] = o;
        }
        if (e8 == 7) *(uint4*)((char*)ldsS + k * (SSTR * 2) + 256) = make_uint4(0,0,0,0);
    }

    // ---- stage x row as 8 shifted bf16 copies (conflict-free write map) ----
    {
        const float* __restrict__ xb = x + (size_t)b * T_LEN;
        const int a = (t ^ (t >> 3)) & 7;
        for (int i = (t >> 3); i < XSTR / 8; i += 128) {
            const int p0 = 8 * i;
            float xv[16];
            if (p0 + 16 <= T_LEN) {
                const float4* sp = (const float4*)(xb + p0);
                #pragma unroll
                for (int j = 0; j < 4; ++j) *(float4*)(xv + 4 * j) = sp[j];
            } else {
                #pragma unroll
                for (int j = 0; j < 16; ++j) {
                    const int gi = p0 + j;
                    xv[j] = (gi < T_LEN) ? xb[gi] : 0.0f;
                }
            }
            unsigned short bv[16];
            #pragma unroll
            for (int j = 0; j < 16; ++j) bv[j] = f2bf(xv[j]);
            uint4 o;
            o.x = pack2(bv[a],     bv[a + 1]);
            o.y = pack2(bv[a + 2], bv[a + 3]);
            o.z = pack2(bv[a + 4], bv[a + 5]);
            o.w = pack2(bv[a + 6], bv[a + 7]);
            *(uint4*)((char*)ldsX + a * (XSTR * 2) + 2 * p0) = o;
        }
    }
    __syncthreads();

    // ---- hoist B fragments: 4 kt16 tiles (64 shapelets) x 4 K-chunks ----
    bf16x8 bfr[4][4];
    #pragma unroll
    for (int kt = 0; kt < 4; ++kt)
        #pragma unroll
        for (int c = 0; c < 4; ++c)
            bfr[kt][c] = __builtin_bit_cast(bf16x8, *(const uint4*)(
                (const char*)ldsS + ((64 * wp + 16 * kt + r)) * (SSTR * 2) + 64 * c + 16 * q));

    // two packed running top-5 sets:
    // rtP: elem0 -> ks = 64wp +      r, elem1 -> ks = 64wp + 16 + r  (kt 0,1)
    // rtQ: elem0 -> ks = 64wp + 32 + r, elem1 -> ks = 64wp + 48 + r  (kt 2,3)
    h2 rtP[5], rtQ[5];
    #pragma unroll
    for (int i = 0; i < 5; ++i) {
        rtP[i] = __builtin_bit_cast(h2, 0xFC00FC00u);
        rtQ[i] = __builtin_bit_cast(h2, 0xFC00FC00u);
    }

    // group G starts at byte 128*G (window 64*G); advances 1024 B (512 windows)
    const char* xp = (const char*)ldsX + c7 * (XSTR * 2) + 16 * q + 16 * ub
                   + G * 128;

    const f32x4 ZCC = (f32x4){0.f, 0.f, 0.f, 0.f};

    // Per step: ONE afr load set feeds TWO kt-pair MFMA passes (R8's LDS win).
#define TILE_STEP                                                               \
    {                                                                           \
        bf16x8 afr[10];                                                         \
        _Pragma("unroll")                                                       \
        for (int j = 0; j < 10; ++j)                                            \
            afr[j] = __builtin_bit_cast(bf16x8, *(const uint4*)(xp + 32 * j));  \
        xp += 1024;                                                             \
        f32x4 acc0[4], acc1[4];                                                 \
        _Pragma("unroll")                                                       \
        for (int m = 0; m < 4; ++m) {                                           \
            acc0[m] = __builtin_amdgcn_mfma_f32_16x16x32_bf16(afr[m], bfr[0][0], ZCC, 0, 0, 0); \
            acc1[m] = __builtin_amdgcn_mfma_f32_16x16x32_bf16(afr[m], bfr[1][0], ZCC, 0, 0, 0); \
        }                                                                       \
        _Pragma("unroll")                                                       \
        for (int c = 1; c < 4; ++c) {                                           \
            _Pragma("unroll")                                                   \
            for (int m = 0; m < 4; ++m) {                                       \
                acc0[m] = __builtin_amdgcn_mfma_f32_16x16x32_bf16(afr[m + 2*c], bfr[0][c], acc0[m], 0, 0, 0); \
                acc1[m] = __builtin_amdgcn_mfma_f32_16x16x32_bf16(afr[m + 2*c], bfr[1][c], acc1[m], 0, 0, 0); \
            }                                                                   \
        }                                                                       \
        select32(acc0, acc1, rtP);                                              \
        _Pragma("unroll")                                                       \
        for (int m = 0; m < 4; ++m) {                                           \
            acc0[m] = __builtin_amdgcn_mfma_f32_16x16x32_bf16(afr[m], bfr[2][0], ZCC, 0, 0, 0); \
            acc1[m] = __builtin_amdgcn_mfma_f32_16x16x32_bf16(afr[m], bfr[3][0], ZCC, 0, 0, 0); \
        }                                                                       \
        _Pragma("unroll")                                                       \
        for (int c = 1; c < 4; ++c) {                                           \
            _Pragma("unroll")                                                   \
            for (int m = 0; m < 4; ++m) {                                       \
                acc0[m] = __builtin_amdgcn_mfma_f32_16x16x32_bf16(afr[m + 2*c], bfr[2][c], acc0[m], 0, 0, 0); \
                acc1[m] = __builtin_amdgcn_mfma_f32_16x16x32_bf16(afr[m + 2*c], bfr[3][c], acc1[m], 0, 0, 0); \
            }                                                                   \
        }                                                                       \
        select32(acc0, acc1, rtQ);                                              \
    }

    // windows 512s + 64G + [0,64): G<6 -> s=0..7, G>=6 -> s=0..6
    const int nst = (G < 6) ? 8 : 7;
    for (int st = 0; st < nst; ++st) { TILE_STEP }
#undef TILE_STEP

    // ---- boundary window n = 3968 (byte 7936) -> G==6 waves (both wp) ----
    if (G == 6) {
        f32x4 e[4];
        #pragma unroll
        for (int kt = 0; kt < 4; ++kt) e[kt] = (f32x4){0.f, 0.f, 0.f, 0.f};
        const char* eb = (const char*)ldsX + c7 * (XSTR * 2) + 7936 + 16 * q + 16 * ub;
        #pragma unroll
        for (int c = 0; c < 4; ++c) {
            const bf16x8 af = __builtin_bit_cast(bf16x8, *(const uint4*)(eb + 64 * c));
            #pragma unroll
            for (int kt = 0; kt < 4; ++kt)
                e[kt] = __builtin_amdgcn_mfma_f32_16x16x32_bf16(af, bfr[kt][c], e[kt], 0, 0, 0);
        }
        if (q == 0) {
            insert1_2(cvt2(e[0][0], e[1][0]), rtP);
            insert1_2(cvt2(e[2][0], e[3][0]), rtQ);
        }
    }

    // ---- butterfly merge across quads for both sets ----
    #pragma unroll
    for (int mask = 16; mask <= 32; mask <<= 1) {
        h2 sv[5], sw[5];
        #pragma unroll
        for (int i = 0; i < 5; ++i) {
            sv[i] = __builtin_bit_cast(h2, __shfl_xor(__builtin_bit_cast(int, rtP[i]), mask));
            sw[i] = __builtin_bit_cast(h2, __shfl_xor(__builtin_bit_cast(int, rtQ[i]), mask));
        }
        merge55_2(rtP[0], rtP[1], rtP[2], rtP[3], rtP[4], sv[0], sv[1], sv[2], sv[3], sv[4]);
        merge55_2(rtQ[0], rtQ[1], rtQ[2], rtQ[3], rtQ[4], sw[0], sw[1], sw[2], sw[3], sw[4]);
    }

    // ---- cross-G merge via LDS; per wp: 7 writers (G!=0), reader G==0 ----
    __syncthreads();   // ldsS reads (bfr hoist) long done; reuse as scratch
    unsigned int* pbuf = (unsigned int*)ldsS;   // [(wp*7 + G-1)*16 + r][10]
    if (G != 0 && q == 0) {
        unsigned int* p = pbuf + ((wp * 7 + (G - 1)) * 16 + r) * 10;
        #pragma unroll
        for (int i = 0; i < 5; ++i) {
            p[i]     = __builtin_bit_cast(unsigned int, rtP[i]);
            p[5 + i] = __builtin_bit_cast(unsigned int, rtQ[i]);
        }
    }
    __syncthreads();
    if (G == 0 && q == 0) {
        #pragma unroll
        for (int reg = 0; reg < 7; ++reg) {
            const unsigned int* p = pbuf + ((wp * 7 + reg) * 16 + r) * 10;
            h2 sv[5], sw[5];
            #pragma unroll
            for (int i = 0; i < 5; ++i) {
                sv[i] = __builtin_bit_cast(h2, p[i]);
                sw[i] = __builtin_bit_cast(h2, p[5 + i]);
            }
            merge55_2(rtP[0], rtP[1], rtP[2], rtP[3], rtP[4], sv[0], sv[1], sv[2], sv[3], sv[4]);
            merge55_2(rtQ[0], rtQ[1], rtQ[2], rtQ[3], rtQ[4], sw[0], sw[1], sw[2], sw[3], sw[4]);
        }

        // emit features for 4 lists: ks = 64wp + {0,16,32,48} + r
        float* ob = out + (size_t)b * (4 * K_SH);
        const h2* rts[2] = { rtP, rtQ };
        #pragma unroll
        for (int setI = 0; setI < 2; ++setI) {
            const h2* rt = rts[setI];
            const float A0 = (float)rt[0][0], A1 = (float)rt[1][0], A2 = (float)rt[2][0],
                        A3 = (float)rt[3][0], A4 = (float)rt[4][0];
            const float B0 = (float)rt[0][1], B1 = (float)rt[1][1], B2 = (float)rt[2][1],
                        B3 = (float)rt[3][1], B4 = (float)rt[4][1];
            const int ksA = 64 * wp + 32 * setI + r, ksB = ksA + 16;
            const float mA = (((A0 + A1) + (A2 + A3)) + A4) * 0.2f;
            const float mB = (((B0 + B1) + (B2 + B3)) + B4) * 0.2f;
            ob[ksA]           = A0;
            ob[K_SH + ksA]    = mA;
            ob[2*K_SH + ksA]  = A1;
            ob[3*K_SH + ksA]  = fmaxf(A0 - A1, 0.0f);
            ob[ksB]           = B0;
            ob[K_SH + ksB]    = mB;
            ob[2*K_SH + ksB]  = B1;
            ob[3*K_SH + ksB]  = fmaxf(B0 - B1, 0.0f);
        }
    }
}

extern "C" void kernel_launch(void* const* d_in, const int* in_sizes, int n_in,
                              void* d_out, int out_size, void* d_ws, size_t ws_size,
                              hipStream_t stream) {
    const float* x = (const float*)d_in[0];        // (256, 4096) fp32
    const float* s = (const float*)d_in[1];        // (128, 128)  fp32
    float* out = (float*)d_out;                    // (256, 512)  fp32
    shapelet_fused16_kernel<<<B_SZ, 1024, 0, stream>>>(x, s, out);
}